// Round 2
// 130.400 us; speedup vs baseline: 1.0245x; 1.0245x over previous
//
#include <hip/hip_runtime.h>
#include <cstdint>

// Problem constants: features (B=4, C=256, H=64, W=64) fp32,
// rois (N=2000, 5) fp32, output (N, C, 7, 7) fp32.
constexpr int CCH = 256;
constexpr int HH  = 64;
constexpr int WW  = 64;
constexpr int OHW = 49;
constexpr float RSCALE = 0.0625f;

// Bit-exact fp32 ops on the coordinate path (xs<64 validity test is the only
// discontinuity in the op).
#define FMUL __fmul_rn
#define FADD __fadd_rn
#define FSUB __fsub_rn
#define FDIV __fdiv_rn

typedef float     v4f __attribute__((ext_vector_type(4)));
typedef _Float16  h2  __attribute__((ext_vector_type(2)));
typedef _Float16  h4  __attribute__((ext_vector_type(4)));

__device__ __forceinline__ h2 pkrtz(float a, float b) {   // v_cvt_pkrtz_f16_f32
  auto t = __builtin_amdgcn_cvt_pkrtz(a, b);
  union { decltype(t) s; h2 d; } c; c.s = t; return c.d;
}
__device__ __forceinline__ h4 bcast4(float a) {           // (a,a,a,a) in fp16
  h2 t = pkrtz(a, a);
  return __builtin_shufflevector(t, t, 0, 1, 0, 1);
}
__device__ __forceinline__ h4 u2h(uint2 u) {              // reinterpret 4xfp16
  union { uint2 u; h4 h; } c; c.u = u; return c.h;
}
__device__ __forceinline__ h4 h4max(h4 a, h4 b) {         // 2x v_pk_max_f16
  return __builtin_elementwise_max(a, b);
}

// ---------------------------------------------------------------------------
// Kernel 1 (fused): transpose+quantize features (B,C,H*W) f32 -> (B,H*W,C)
// fp16 (r11: was bf16 — fp16 halves quantization error 2^-8 -> 2^-11 rel and
// converts with 1 v_cvt instead of the 4-instr manual RNE), PLUS the roi
// scheduling pass as one extra grid slice (z==B, block (0,0)).
// Scheduling (XCD-batch affinity, 2 blocks/roi): roi block i -> XCD i%8;
// pair p=(i&7)>>1 gets batch-p rois so each XCD's gather set is one 2.1 MB
// slice (< 4 MiB XCD L2). slot s=i>>3.
// meta: [0..3]=cnt [4..7]=off [8..11]=cumslack; perm[N]; extra[N].
// ---------------------------------------------------------------------------
__global__ __launch_bounds__(256) void ktrans_sched(const float* __restrict__ in,
                                                    unsigned short* __restrict__ out,
                                                    const float* __restrict__ rois,
                                                    int N, int slots, int do_sched,
                                                    int B, int* __restrict__ meta) {
  const int t = threadIdx.x;

  if ((int)blockIdx.z == B) {
    if (blockIdx.x != 0 || blockIdx.y != 0 || !do_sched) return;
    __shared__ int cnt[4], rnk[4], off[4], slack[4], excess[4];
    if (t < 4) { cnt[t] = 0; rnk[t] = 0; }
    __syncthreads();
    for (int i = t; i < N; i += 256) atomicAdd(&cnt[(int)rois[i * 5]], 1);
    __syncthreads();
    if (t == 0) {
      int o = 0, cs = 0, ce = 0;
      for (int p = 0; p < 4; ++p) {
        off[p] = o; o += cnt[p];
        slack[p]  = cs; if (slots - cnt[p] > 0) cs += slots - cnt[p];
        excess[p] = ce; if (cnt[p] - slots > 0) ce += cnt[p] - slots;
        meta[p] = cnt[p]; meta[4 + p] = off[p]; meta[8 + p] = slack[p];
      }
    }
    __syncthreads();
    int* perm = meta + 16;
    for (int i = t; i < N; i += 256) {
      const int b = (int)rois[i * 5];
      perm[off[b] + atomicAdd(&rnk[b], 1)] = i;
    }
    __syncthreads();
    int* extra = meta + 16 + N;
    for (int p = 0; p < 4; ++p) {
      const int ex = cnt[p] - slots;
      for (int e = t; e < ex; e += 256) extra[excess[p] + e] = perm[off[p] + slots + e];
    }
    return;
  }

  __shared__ float tile[64][65];
  const int b  = blockIdx.z;
  const int c0 = blockIdx.y * 64;
  const int s0 = blockIdx.x * 64;
  const float* inb = in + (size_t)b * CCH * (HH * WW);
  unsigned short* outb = out + (size_t)b * (HH * WW) * CCH;

  const int cl = t >> 4, sq = t & 15;
#pragma unroll
  for (int k = 0; k < 4; ++k) {
    const int c = cl + 16 * k;
    const v4f v = __builtin_nontemporal_load(
        (const v4f*)(inb + (size_t)(c0 + c) * (HH * WW) + s0 + 4 * sq));
    tile[c][4 * sq + 0] = v[0];
    tile[c][4 * sq + 1] = v[1];
    tile[c][4 * sq + 2] = v[2];
    tile[c][4 * sq + 3] = v[3];
  }
  __syncthreads();
  const int cq = t & 15, rl = t >> 4;
#pragma unroll
  for (int k = 0; k < 4; ++k) {
    const int r = rl + 16 * k;
    union { h2 h; unsigned u; } p0, p1;
    p0.h.x = (_Float16)tile[4 * cq + 0][r];   // v_cvt_f16_f32 (RNE)
    p0.h.y = (_Float16)tile[4 * cq + 1][r];
    p1.h.x = (_Float16)tile[4 * cq + 2][r];
    p1.h.y = (_Float16)tile[4 * cq + 3][r];
    uint2 w; w.x = p0.u; w.y = p1.u;
    *(uint2*)(outb + (size_t)(s0 + r) * CCH + c0 + 4 * cq) = w;
  }
}

// ---------------------------------------------------------------------------
// Kernel 2 (r11): RoIAlign + 2x2 s1 maxpool, packed-fp16 datapath.
//  - Gathered uint2 IS two half2 registers: interp = 8 v_pk_fma_f16 per q
//    (was 16 unpack + 16 f32 fma). Weights computed in f32 (coord path stays
//    bit-exact), single-rounded via v_cvt_pkrtz broadcast.
//  - Maxpool + phase A/B in v_pk_max_f16 (monotone => quantize-before-max
//    exact); hc = 14 VGPR (was 28); A/B LDS traffic halved (b64).
//  - Phase C/D FLIPPED: C scatters with immediate-offset ds_write_b16 into an
//    fp16 out-linear LDS image (zero address VALU, ~2-way banks = free);
//    D is contiguous ds_read_b64 + 4 cvt + nontemporal dwordx4 store.
//    Deletes the whole magic-div (e/49) + XOR-swizzle block (~190 instr/thd).
//  - ldsA (A/B share) and ldsC (out image) are DISJOINT 12,544 B regions:
//    2 barriers suffice with no aliasing argument. Total LDS 25,088 B
//    unchanged -> still 6 blocks/CU (VGPR-capped at 6 waves/SIMD anyway).
//  - Output stores nontemporal: 100 MB stream no longer evicts the 2.1 MB/XCD
//    fp16 feature slice from L2, so gathers stay L2-hit.
// ---------------------------------------------------------------------------
__global__ __launch_bounds__(256, 6) void roi_kernel11(const uint2* __restrict__ feat,
                                                       const float* __restrict__ rois,
                                                       const int* __restrict__ meta,
                                                       int N, int use_perm,
                                                       float* __restrict__ out) {
  __shared__ __attribute__((aligned(16))) h4       ldsA[OHW * 32];          // 12544 B
  __shared__ __attribute__((aligned(16))) _Float16 ldsC[(CCH / 2) * OHW];   // 12544 B
  const int i = blockIdx.x;
  const int t = threadIdx.x;
  const int g = t & 31;                        // granule within half (4 ch)
  const int r = t >> 5;                        // sample row 0..7

  int n, half;
  if (use_perm) {
    const int p = (i & 7) >> 1;
    half        = i & 1;
    const int s = i >> 3;
    const int c_ = meta[p];
    const int o_ = meta[4 + p];
    const int sl = meta[8 + p];
    const int* perm  = meta + 16;
    const int* extra = meta + 16 + N;
    n = (s < c_) ? perm[o_ + s] : extra[sl + (s - c_)];
  } else {
    n = i >> 1; half = i & 1;
  }

  const float rb = rois[n * 5 + 0];
  const float x1 = FMUL(rois[n * 5 + 1], RSCALE);
  const float y1 = FMUL(rois[n * 5 + 2], RSCALE);
  const float x2 = FMUL(rois[n * 5 + 3], RSCALE);
  const float y2 = FMUL(rois[n * 5 + 4], RSCALE);
  const int   b  = (int)rb;
  const float bh = FDIV(FSUB(y2, y1), 7.0f);
  const float bw = FDIV(FSUB(x2, x1), 7.0f);

  int   xo0[8], xo1[8];
  float lx[8];
  bool  xv[8];
#pragma unroll
  for (int q = 0; q < 8; ++q) {
    const float xs = FADD(x1, FMUL(bw, (float)q));
    xv[q] = (xs >= 0.0f) && (xs < (float)WW);
    const float xf = floorf(xs);
    lx[q] = FSUB(xs, xf);
    int a = (int)xf;
    a = a < 0 ? 0 : (a > WW - 1 ? WW - 1 : a);
    xo0[q] = a * (CCH / 4);
    xo1[q] = ((a + 1 > WW - 1) ? WW - 1 : a + 1) * (CCH / 4);
  }

  const float ys = FADD(y1, FMUL(bh, (float)r));
  const bool  yv = (ys >= 0.0f) && (ys < (float)HH);
  const float yf = floorf(ys);
  const float ly = FSUB(ys, yf);
  int d = (int)yf;
  d = d < 0 ? 0 : (d > HH - 1 ? HH - 1 : d);
  const int d1 = (d + 1 > HH - 1) ? HH - 1 : d + 1;

  const uint2* fb = feat + (size_t)b * (HH * WW) * (CCH / 4) + (half * 32 + g);
  const uint2* r0 = fb + (size_t)d  * (WW * (CCH / 4));
  const uint2* r1 = fb + (size_t)d1 * (WW * (CCH / 4));
  const float wy1 = ly, wy0 = 1.0f - ly;

  h4 hc[7], vprev;
#pragma unroll
  for (int h = 0; h < 2; ++h) {
    uint2 g00[4], g01[4], g10[4], g11[4];
#pragma unroll
    for (int q = 0; q < 4; ++q) {
      const int s = 4 * h + q;
      g00[q] = r0[xo0[s]];
      g01[q] = r0[xo1[s]];
      g10[q] = r1[xo0[s]];
      g11[q] = r1[xo1[s]];
    }
    h4 v[4];
#pragma unroll
    for (int q = 0; q < 4; ++q) {
      const int s = 4 * h + q;
      const bool ok = yv && xv[s];
      const float wx1 = lx[s], wx0 = 1.0f - wx1;
      const h4 w00 = bcast4(wy0 * wx0);        // f32 product, 1 rounding to fp16
      const h4 w01 = bcast4(wy0 * wx1);
      const h4 w10 = bcast4(wy1 * wx0);
      const h4 w11 = bcast4(wy1 * wx1);
      h4 rr = w00 * u2h(g00[q]) + w01 * u2h(g01[q])
            + w10 * u2h(g10[q]) + w11 * u2h(g11[q]);   // 8x v_pk_{mul,fma}_f16
      v[q] = ok ? rr : h4{};
    }
    if (h == 0) {
      hc[0] = h4max(v[0], v[1]);
      hc[1] = h4max(v[1], v[2]);
      hc[2] = h4max(v[2], v[3]);
      vprev = v[3];
    } else {
      hc[3] = h4max(vprev, v[0]);
      hc[4] = h4max(v[0], v[1]);
      hc[5] = h4max(v[1], v[2]);
      hc[6] = h4max(v[2], v[3]);
    }
  }

  // ---- phase A: row r>=1 publishes hc at slot r-1 (ds_write_b64) ----
  if (r >= 1) {
#pragma unroll
    for (int m = 0; m < 7; ++m)
      ldsA[((r - 1) * 7 + m) * 32 + g] = hc[m];
  }
  __syncthreads();                             // A->B: cross-wave publish

  // ---- phase B+C fused: row r<=6 maxes with row r+1's hc (b64 read +
  //      pk_max) and scatters the result into the fp16 out-linear image with
  //      immediate-offset ds_write_b16. ldsA/ldsC disjoint -> no barrier
  //      needed between B and C. ----
  if (r <= 6) {
    _Float16* cb = ldsC + (4 * g) * OHW + r * 7;   // channel 4g, out row r
#pragma unroll
    for (int m = 0; m < 7; ++m) {
      const h4 x = h4max(hc[m], ldsA[(r * 7 + m) * 32 + g]);
      cb[0 * OHW + m] = x[0];
      cb[1 * OHW + m] = x[1];
      cb[2 * OHW + m] = x[2];
      cb[3 * OHW + m] = x[3];
    }
  }
  __syncthreads();                             // C->D: cross-wave writeback

  // ---- phase D: contiguous b64 read -> 4x cvt -> nontemporal dwordx4.
  //      1568 float4 over 256 threads, no div/mod, no swizzle. ----
  const uint2* cs = (const uint2*)ldsC;
  v4f* o4 = (v4f*)(out + (size_t)n * (CCH * OHW) + half * (CCH / 2) * OHW);
#pragma unroll
  for (int m = 0; m < 7; ++m) {
    const int idx = m * 256 + t;
    if (idx < (CCH / 2) * OHW / 4) {
      const uint2 qv = cs[idx];
      union { unsigned u; h2 h; } c0, c1;
      c0.u = qv.x; c1.u = qv.y;
      v4f wv;
      wv.x = (float)c0.h.x;
      wv.y = (float)c0.h.y;
      wv.z = (float)c1.h.x;
      wv.w = (float)c1.h.y;
      __builtin_nontemporal_store(wv, o4 + idx);
    }
  }
}

// ---------------------------------------------------------------------------
// Fallback (workspace too small): round-2 scalar path, known-correct.
// ---------------------------------------------------------------------------
__global__ __launch_bounds__(256) void roi_kernel_fb(const float* __restrict__ feat,
                                                     const float* __restrict__ rois,
                                                     float* __restrict__ out) {
  __shared__ float sout[CCH * OHW];
  const int n = blockIdx.x;
  const int c = threadIdx.x;

  const float rb = rois[n * 5 + 0];
  const float x1 = FMUL(rois[n * 5 + 1], RSCALE);
  const float y1 = FMUL(rois[n * 5 + 2], RSCALE);
  const float x2 = FMUL(rois[n * 5 + 3], RSCALE);
  const float y2 = FMUL(rois[n * 5 + 4], RSCALE);
  const int b = (int)rb;
  const float bh = FDIV(FSUB(y2, y1), 7.0f);
  const float bw = FDIV(FSUB(x2, x1), 7.0f);

  int ix0[8], ix1[8], iy0[8], iy1[8];
  float lx[8], ly[8];
  bool xv[8], yv[8];
#pragma unroll
  for (int i = 0; i < 8; ++i) {
    const float xs = FADD(x1, FMUL(bw, (float)i));
    const float ys = FADD(y1, FMUL(bh, (float)i));
    xv[i] = (xs >= 0.0f) && (xs < (float)WW);
    yv[i] = (ys >= 0.0f) && (ys < (float)HH);
    const float xf = floorf(xs);
    const float yf = floorf(ys);
    lx[i] = FSUB(xs, xf);
    ly[i] = FSUB(ys, yf);
    int a = (int)xf;
    a = a < 0 ? 0 : (a > WW - 1 ? WW - 1 : a);
    ix0[i] = a;
    ix1[i] = (a + 1 > WW - 1) ? WW - 1 : a + 1;
    int d = (int)yf;
    d = d < 0 ? 0 : (d > HH - 1 ? HH - 1 : d);
    iy0[i] = d;
    iy1[i] = (d + 1 > HH - 1) ? HH - 1 : d + 1;
  }

  const float* fbp = feat + ((size_t)b * CCH + c) * (size_t)(HH * WW);
  float hp[7];
#pragma unroll
  for (int j = 0; j < 8; ++j) {
    float v[8];
    const float wy1 = ly[j], wy0 = 1.0f - ly[j];
#pragma unroll
    for (int i = 0; i < 8; ++i) {
      if (yv[j] && xv[i]) {
        const float f00 = fbp[iy0[j] * WW + ix0[i]];
        const float f01 = fbp[iy0[j] * WW + ix1[i]];
        const float f10 = fbp[iy1[j] * WW + ix0[i]];
        const float f11 = fbp[iy1[j] * WW + ix1[i]];
        const float wx1 = lx[i], wx0 = 1.0f - wx1;
        v[i] = wy0 * (wx0 * f00 + wx1 * f01) + wy1 * (wx0 * f10 + wx1 * f11);
      } else {
        v[i] = 0.0f;
      }
    }
    float hc[7];
#pragma unroll
    for (int i = 0; i < 7; ++i) hc[i] = fmaxf(v[i], v[i + 1]);
    if (j > 0) {
#pragma unroll
      for (int i = 0; i < 7; ++i)
        sout[c * OHW + (j - 1) * 7 + i] = fmaxf(hp[i], hc[i]);
    }
#pragma unroll
    for (int i = 0; i < 7; ++i) hp[i] = hc[i];
  }
  __syncthreads();
  const float4* s4 = (const float4*)sout;
  float4* o4 = (float4*)(out + (size_t)n * (CCH * OHW));
  for (int q = c; q < (CCH * OHW) / 4; q += 256) o4[q] = s4[q];
}

extern "C" void kernel_launch(void* const* d_in, const int* in_sizes, int n_in,
                              void* d_out, int out_size, void* d_ws, size_t ws_size,
                              hipStream_t stream) {
  (void)n_in; (void)out_size;
  const float* feat = (const float*)d_in[0];
  const float* rois = (const float*)d_in[1];
  float* out = (float*)d_out;
  const int N = in_sizes[1] / 5;
  const int B = in_sizes[0] / (CCH * HH * WW);
  const int M = 2 * N;                                  // roi blocks (2/roi)
  const size_t featbf_bytes = (size_t)in_sizes[0] * sizeof(unsigned short);
  const size_t meta_bytes   = (size_t)(16 + 2 * N) * sizeof(int);

  if (ws_size >= featbf_bytes + meta_bytes) {
    unsigned short* featbf = (unsigned short*)d_ws;
    int* meta = (int*)((char*)d_ws + featbf_bytes);
    const int use_perm = (B == 4 && (M & 7) == 0) ? 1 : 0;

    ktrans_sched<<<dim3((HH * WW) / 64, CCH / 64, B + 1), dim3(256), 0, stream>>>(
        feat, featbf, rois, N, M >> 3, use_perm, B, meta);
    roi_kernel11<<<dim3(M), dim3(256), 0, stream>>>(
        (const uint2*)featbf, rois, meta, N, use_perm, out);
  } else {
    roi_kernel_fb<<<dim3(N), dim3(256), 0, stream>>>(feat, rois, out);
  }
}